// Round 5
// baseline (211.722 us; speedup 1.0000x reference)
//
#include <hip/hip_runtime.h>
#include <math.h>

typedef float v2 __attribute__((ext_vector_type(2)));

// B=128, IN=256, H=1024 -> 128 steps of (layerA, layerB). nA=512, nB=511.
#define NBATCH 128
#define NIN    256
#define NH     1024
#define NSTEPS 128
#define NB     511

// Angle table: [layer][j(0..15)][lane(0..63)] float4 {c0,s0,c1,s1}
//   j 0..7  : A pair 8*lane+j
//   j 8..15 : B pair 8*lane+(j-8)   (slot (15,63)=pair 511 -> identity)
// Left-boundary angles (pair 8*lane-1) are obtained in-kernel by shuffling
// T[15] up one lane (lane 0 -> identity). Table = 2 MB; ih = 1 MB; total 3 MB.
#define TAB_F4_PER_L 1024
#define IH_OFF (NSTEPS * TAB_F4_PER_L * 4)   // float offset; ih float4 = {R,I,R,I}

#define GEMM_BLOCKS 256
#define TRIG_BLOCKS 512                      // 512*256 = 128*1024 exactly

static __device__ __forceinline__ v2 to2(float a, float b) { v2 r; r.x = a; r.y = b; return r; }

// ---------------------------------------------------------------------------
// prep: blocks [0,256) complex gemm ih = in @ W^T + bias; [256,768) trig table
// (verbatim from round 4 — passed)
// ---------------------------------------------------------------------------
__global__ __launch_bounds__(256) void prep_kernel(
    const float* __restrict__ inR, const float* __restrict__ inI,
    const float* __restrict__ wR,  const float* __restrict__ wI,
    const float* __restrict__ biasR, const float* __restrict__ biasI,
    const float* __restrict__ A0, const float* __restrict__ A1,
    const float* __restrict__ B0, const float* __restrict__ B1,
    float* __restrict__ ws)
{
    __shared__ v2 xs[256][17];   // [k][b]  {xr,xi}
    __shared__ v2 wsh[32][34];   // [k][h]  {wr,wi}; stride 34 v2 = 272 B

    if (blockIdx.x >= GEMM_BLOCKS) {
        int idx = (blockIdx.x - GEMM_BLOCKS) * 256 + threadIdx.x;
        int l = idx >> 10;
        int s = idx & 1023;
        int j = s >> 6, lane = s & 63;
        float a0, a1;
        bool ident = false;
        if (j < 8) {
            int p = 8 * lane + j;
            a0 = A0[l * 512 + p]; a1 = A1[l * 512 + p];
        } else {
            int p = 8 * lane + (j - 8);
            if (p < NB) { a0 = B0[l * NB + p]; a1 = B1[l * NB + p]; }
            else ident = true;
        }
        float4 v;
        if (ident) v = make_float4(1.f, 0.f, 1.f, 0.f);
        else {
            float s0, c0, s1, c1;
            __sincosf(a0, &s0, &c0);
            __sincosf(a1, &s1, &c1);
            v = make_float4(c0, s0, c1, s1);
        }
        ((float4*)ws)[l * TAB_F4_PER_L + j * 64 + lane] = v;
        return;
    }

    const int ht = blockIdx.x >> 3, bt = blockIdx.x & 7;
    const int h0 = ht * 32, b0 = bt * 16;
    const int tid = threadIdx.x;

    {
        int b = tid >> 4, k4 = tid & 15;
#pragma unroll
        for (int p = 0; p < 4; ++p) {
            int k0 = p * 64 + k4 * 4;
            float4 vr = *(const float4*)(inR + (b0 + b) * NIN + k0);
            float4 vi = *(const float4*)(inI + (b0 + b) * NIN + k0);
            xs[k0 + 0][b] = to2(vr.x, vi.x);
            xs[k0 + 1][b] = to2(vr.y, vi.y);
            xs[k0 + 2][b] = to2(vr.z, vi.z);
            xs[k0 + 3][b] = to2(vr.w, vi.w);
        }
    }

    const int hg = tid & 15, bl = tid >> 4;
    v2 acc0 = to2(0.f, 0.f), acc1 = to2(0.f, 0.f);

    for (int c = 0; c < 8; ++c) {
        __syncthreads();
        {
            int hh = tid >> 3, k4 = tid & 7;
            float4 vr = *(const float4*)(wR + (h0 + hh) * NIN + c * 32 + k4 * 4);
            float4 vi = *(const float4*)(wI + (h0 + hh) * NIN + c * 32 + k4 * 4);
            wsh[k4 * 4 + 0][hh] = to2(vr.x, vi.x);
            wsh[k4 * 4 + 1][hh] = to2(vr.y, vi.y);
            wsh[k4 * 4 + 2][hh] = to2(vr.z, vi.z);
            wsh[k4 * 4 + 3][hh] = to2(vr.w, vi.w);
        }
        __syncthreads();
#pragma unroll
        for (int k = 0; k < 32; ++k) {
            float4 wv = *(const float4*)&wsh[k][hg * 2];
            v2 w0 = to2(wv.x, wv.y), w1 = to2(wv.z, wv.w);
            v2 xv = xs[c * 32 + k][bl];
            acc0 += to2(xv.x, xv.x) * w0 + to2(xv.y, xv.y) * to2(-w0.y, w0.x);
            acc1 += to2(xv.x, xv.x) * w1 + to2(xv.y, xv.y) * to2(-w1.y, w1.x);
        }
    }
    int h = h0 + hg * 2, b = b0 + bl;
    acc0 += to2(biasR[h], biasI[h]);
    acc1 += to2(biasR[h + 1], biasI[h + 1]);
    ((float4*)(ws + IH_OFF))[b * 512 + (h >> 1)] =
        make_float4(acc0.x, acc0.y, acc1.x, acc1.y);
}

// ---------------------------------------------------------------------------
// mesh: one wave per batch row, 16 channels/lane, pk-fp32 MZIs, shuffle
// boundaries. Angle table streamed via global_load_lds DMA into a 4-slot
// LDS ring with prefetch distance 3 and hand-placed vmcnt waits (never 0
// in steady state) -> miss latency off the critical path, zero VGPR cost.
// ---------------------------------------------------------------------------
__device__ __forceinline__ void mzi(const float4 t, v2& a, v2& b)
{
    v2 P  = to2(t.x, t.y) * to2(a.x, a.x) + to2(-t.y, t.x) * to2(a.y, a.y);
    v2 na = to2(t.z, t.z) * P + to2(-t.w, t.w) * to2(b.y, b.x);
    b     = to2(t.z, t.z) * b + to2(-t.w, t.w) * to2(P.y, P.x);
    a = na;
}

__device__ __forceinline__ void step(v2* x, const float4* T, int lane)
{
    mzi(T[0], x[0], x[1]);
    mzi(T[7], x[14], x[15]);
    float rc0r  = __shfl_down(x[0].x, 1, 64);
    float rc0i  = __shfl_down(x[0].y, 1, 64);
    float lc15r = __shfl_up(x[15].x, 1, 64);
    float lc15i = __shfl_up(x[15].y, 1, 64);
    float blx = __shfl_up(T[15].x, 1, 64);
    float bly = __shfl_up(T[15].y, 1, 64);
    float blz = __shfl_up(T[15].z, 1, 64);
    float blw = __shfl_up(T[15].w, 1, 64);
    if (lane == 0) { blx = 1.f; bly = 0.f; blz = 1.f; blw = 0.f; }
#pragma unroll
    for (int j = 1; j < 7; ++j) mzi(T[j], x[2 * j], x[2 * j + 1]);
#pragma unroll
    for (int j = 0; j < 7; ++j) mzi(T[8 + j], x[2 * j + 1], x[2 * j + 2]);
    {
        const float4 t = T[15];
        v2 P = to2(t.x, t.y) * to2(x[15].x, x[15].x) + to2(-t.y, t.x) * to2(x[15].y, x[15].y);
        x[15] = to2(t.z, t.z) * P + to2(-t.w, t.w) * to2(rc0i, rc0r);
    }
    {
        v2 P = to2(blx, bly) * to2(lc15r, lc15r) + to2(-bly, blx) * to2(lc15i, lc15i);
        x[0] = to2(blz, blz) * x[0] + to2(-blw, blw) * to2(P.y, P.x);
    }
}

#define GLOBAL_AS const __attribute__((address_space(1))) void*
#define LDS_AS    __attribute__((address_space(3))) void*

__global__ __launch_bounds__(64, 1) void mesh_kernel(
    const float* __restrict__ stateR, const float* __restrict__ stateI,
    const float* __restrict__ omega,  const float* __restrict__ mod_bias,
    const float* __restrict__ ws, float* __restrict__ out)
{
    // 4-slot ring: [slot][j][lane] float4  = 4 x 16 KB = 64 KB
    __shared__ float4 smem[4][16][64];

    const int b = blockIdx.x;
    const int lane = threadIdx.x;
    const float4* tab = (const float4*)ws;

    v2 x[16];
    {
        const float4* sr4 = (const float4*)(stateR + b * NH + lane * 16);
        const float4* si4 = (const float4*)(stateI + b * NH + lane * 16);
#pragma unroll
        for (int q = 0; q < 4; ++q) {
            float4 r = sr4[q], i = si4[q];
            x[4 * q + 0] = to2(r.x, i.x);
            x[4 * q + 1] = to2(r.y, i.y);
            x[4 * q + 2] = to2(r.z, i.z);
            x[4 * q + 3] = to2(r.w, i.w);
        }
    }

    // DMA one layer's 16 KB into ring slot (l & 3): 16 x dwordx4, lane i
    // lands at slot base + j*1KB + i*16 — exactly the [j][lane] layout.
#define ISSUE_LAYER(l)                                                        \
    do {                                                                      \
        const float4* _src = tab + (l) * TAB_F4_PER_L + lane;                 \
        _Pragma("unroll") for (int _j = 0; _j < 16; ++_j)                     \
            __builtin_amdgcn_global_load_lds(                                 \
                (GLOBAL_AS)(_src + _j * 64),                                  \
                (LDS_AS)&smem[(l) & 3][_j][0], 16, 0, 0);                     \
    } while (0)

    ISSUE_LAYER(0);
    ISSUE_LAYER(1);
    ISSUE_LAYER(2);

    for (int l = 0; l < NSTEPS; ++l) {
        if (l < NSTEPS - 3) {
            ISSUE_LAYER(l + 3);
            // newest 48 outstanding = layers l+1..l+3 -> layer l landed
            asm volatile("s_waitcnt vmcnt(48)" ::: "memory");
        } else if (l == NSTEPS - 3) {
            asm volatile("s_waitcnt vmcnt(32)" ::: "memory");
        } else if (l == NSTEPS - 2) {
            asm volatile("s_waitcnt vmcnt(16)" ::: "memory");
        } else {
            asm volatile("s_waitcnt vmcnt(0)" ::: "memory");
        }
        float4 T[16];
        const int slot = l & 3;
#pragma unroll
        for (int j = 0; j < 16; ++j) T[j] = smem[slot][j][lane];
        step(x, T, lane);
    }

    // epilogue: phase, + ih, modReLU
    float om[16], mb[16];
#pragma unroll
    for (int q = 0; q < 4; ++q) {
        float4 o = ((const float4*)(omega + lane * 16))[q];
        float4 m = ((const float4*)(mod_bias + lane * 16))[q];
        om[4 * q] = o.x; om[4 * q + 1] = o.y; om[4 * q + 2] = o.z; om[4 * q + 3] = o.w;
        mb[4 * q] = m.x; mb[4 * q + 1] = m.y; mb[4 * q + 2] = m.z; mb[4 * q + 3] = m.w;
    }
    float o0[16], o1[16];
    const float4* ihp = (const float4*)(ws + IH_OFF + b * NH * 2) + lane * 8;
#pragma unroll
    for (int q = 0; q < 8; ++q) {
        float4 ih2 = ihp[q];   // {R,I} for channels 2q, 2q+1
#pragma unroll
        for (int e = 0; e < 2; ++e) {
            int j = 2 * q + e;
            float ihr = (e == 0) ? ih2.x : ih2.z;
            float ihi = (e == 0) ? ih2.y : ih2.w;
            float so, co;
            __sincosf(om[j], &so, &co);
            float zr = ihr + co * x[j].x - so * x[j].y;
            float zi = ihi + so * x[j].x + co * x[j].y;
            float mag = sqrtf(zr * zr + zi * zi);
            float sc = fmaxf(mag + mb[j], 0.f) / fmaxf(mag, 1e-8f);
            o0[j] = sc * zr;
            o1[j] = sc * zi;
        }
    }
#pragma unroll
    for (int q = 0; q < 4; ++q) {
        ((float4*)(out + b * NH + lane * 16))[q] =
            make_float4(o0[4 * q], o0[4 * q + 1], o0[4 * q + 2], o0[4 * q + 3]);
        ((float4*)(out + NBATCH * NH + b * NH + lane * 16))[q] =
            make_float4(o1[4 * q], o1[4 * q + 1], o1[4 * q + 2], o1[4 * q + 3]);
    }
}

// ---------------------------------------------------------------------------
extern "C" void kernel_launch(void* const* d_in, const int* in_sizes, int n_in,
                              void* d_out, int out_size, void* d_ws, size_t ws_size,
                              hipStream_t stream)
{
    const float* inputsR = (const float*)d_in[0];
    const float* inputsI = (const float*)d_in[1];
    const float* stateR  = (const float*)d_in[2];
    const float* stateI  = (const float*)d_in[3];
    const float* weightR = (const float*)d_in[4];
    const float* weightI = (const float*)d_in[5];
    const float* biasR   = (const float*)d_in[6];
    const float* biasI   = (const float*)d_in[7];
    const float* angleA0 = (const float*)d_in[8];
    const float* angleA1 = (const float*)d_in[9];
    const float* angleB0 = (const float*)d_in[10];
    const float* angleB1 = (const float*)d_in[11];
    const float* omega   = (const float*)d_in[12];
    const float* mod_b   = (const float*)d_in[13];
    float* ws = (float*)d_ws;
    float* out = (float*)d_out;

    hipLaunchKernelGGL(prep_kernel, dim3(GEMM_BLOCKS + TRIG_BLOCKS), dim3(256),
                       0, stream, inputsR, inputsI, weightR, weightI,
                       biasR, biasI, angleA0, angleA1, angleB0, angleB1, ws);
    hipLaunchKernelGGL(mesh_kernel, dim3(NBATCH), dim3(64), 0, stream,
                       stateR, stateI, omega, mod_b, ws, out);
}

// Round 9
// 169.087 us; speedup vs baseline: 1.2521x; 1.2521x over previous
//
#include <hip/hip_runtime.h>
#include <math.h>

typedef float v2 __attribute__((ext_vector_type(2)));

// B=128, IN=256, H=1024 -> 128 steps of (layerA, layerB). nA=512, nB=511.
#define NBATCH 128
#define NIN    256
#define NH     1024
#define NSTEPS 128
#define NB     511

// Angle table: [layer][j(0..15)][lane(0..63)] float4 {c0,s0,c1,s1}
//   j 0..7  : A pair 8*lane+j
//   j 8..15 : B pair 8*lane+(j-8)   (slot (15,63)=pair 511 -> identity)
// Left-boundary angles (pair 8*lane-1) come from shuffling T[15] up one lane
// (lane 0 -> identity). Table = 2 MB; ih = 1 MB; total 3 MB.
#define TAB_F4_PER_L 1024
#define IH_OFF (NSTEPS * TAB_F4_PER_L * 4)   // float offset; ih float4 = {R,I,R,I}

#define GEMM_BLOCKS 256
#define TRIG_BLOCKS 512                      // 512*256 = 128*1024 exactly

static __device__ __forceinline__ v2 to2(float a, float b) { v2 r; r.x = a; r.y = b; return r; }

// ---------------------------------------------------------------------------
// prep: blocks [0,256) complex gemm ih = in @ W^T + bias; [256,768) trig table
// (verbatim from round 4 — passed)
// ---------------------------------------------------------------------------
__global__ __launch_bounds__(256) void prep_kernel(
    const float* __restrict__ inR, const float* __restrict__ inI,
    const float* __restrict__ wR,  const float* __restrict__ wI,
    const float* __restrict__ biasR, const float* __restrict__ biasI,
    const float* __restrict__ A0, const float* __restrict__ A1,
    const float* __restrict__ B0, const float* __restrict__ B1,
    float* __restrict__ ws)
{
    __shared__ v2 xs[256][17];   // [k][b]  {xr,xi}
    __shared__ v2 wsh[32][34];   // [k][h]  {wr,wi}; stride 34 v2 = 272 B

    if (blockIdx.x >= GEMM_BLOCKS) {
        int idx = (blockIdx.x - GEMM_BLOCKS) * 256 + threadIdx.x;
        int l = idx >> 10;
        int s = idx & 1023;
        int j = s >> 6, lane = s & 63;
        float a0, a1;
        bool ident = false;
        if (j < 8) {
            int p = 8 * lane + j;
            a0 = A0[l * 512 + p]; a1 = A1[l * 512 + p];
        } else {
            int p = 8 * lane + (j - 8);
            if (p < NB) { a0 = B0[l * NB + p]; a1 = B1[l * NB + p]; }
            else ident = true;
        }
        float4 v;
        if (ident) v = make_float4(1.f, 0.f, 1.f, 0.f);
        else {
            float s0, c0, s1, c1;
            __sincosf(a0, &s0, &c0);
            __sincosf(a1, &s1, &c1);
            v = make_float4(c0, s0, c1, s1);
        }
        ((float4*)ws)[l * TAB_F4_PER_L + j * 64 + lane] = v;
        return;
    }

    const int ht = blockIdx.x >> 3, bt = blockIdx.x & 7;
    const int h0 = ht * 32, b0 = bt * 16;
    const int tid = threadIdx.x;

    {
        int b = tid >> 4, k4 = tid & 15;
#pragma unroll
        for (int p = 0; p < 4; ++p) {
            int k0 = p * 64 + k4 * 4;
            float4 vr = *(const float4*)(inR + (b0 + b) * NIN + k0);
            float4 vi = *(const float4*)(inI + (b0 + b) * NIN + k0);
            xs[k0 + 0][b] = to2(vr.x, vi.x);
            xs[k0 + 1][b] = to2(vr.y, vi.y);
            xs[k0 + 2][b] = to2(vr.z, vi.z);
            xs[k0 + 3][b] = to2(vr.w, vi.w);
        }
    }

    const int hg = tid & 15, bl = tid >> 4;
    v2 acc0 = to2(0.f, 0.f), acc1 = to2(0.f, 0.f);

    for (int c = 0; c < 8; ++c) {
        __syncthreads();
        {
            int hh = tid >> 3, k4 = tid & 7;
            float4 vr = *(const float4*)(wR + (h0 + hh) * NIN + c * 32 + k4 * 4);
            float4 vi = *(const float4*)(wI + (h0 + hh) * NIN + c * 32 + k4 * 4);
            wsh[k4 * 4 + 0][hh] = to2(vr.x, vi.x);
            wsh[k4 * 4 + 1][hh] = to2(vr.y, vi.y);
            wsh[k4 * 4 + 2][hh] = to2(vr.z, vi.z);
            wsh[k4 * 4 + 3][hh] = to2(vr.w, vi.w);
        }
        __syncthreads();
#pragma unroll
        for (int k = 0; k < 32; ++k) {
            float4 wv = *(const float4*)&wsh[k][hg * 2];
            v2 w0 = to2(wv.x, wv.y), w1 = to2(wv.z, wv.w);
            v2 xv = xs[c * 32 + k][bl];
            acc0 += to2(xv.x, xv.x) * w0 + to2(xv.y, xv.y) * to2(-w0.y, w0.x);
            acc1 += to2(xv.x, xv.x) * w1 + to2(xv.y, xv.y) * to2(-w1.y, w1.x);
        }
    }
    int h = h0 + hg * 2, b = b0 + bl;
    acc0 += to2(biasR[h], biasI[h]);
    acc1 += to2(biasR[h + 1], biasI[h + 1]);
    ((float4*)(ws + IH_OFF))[b * 512 + (h >> 1)] =
        make_float4(acc0.x, acc0.y, acc1.x, acc1.y);
}

// ---------------------------------------------------------------------------
// mesh: one wave per batch row, 16 channels/lane, pk-fp32 MZIs, shuffle
// boundaries. Angles stream via global_load_lds DMA into a 4-slot LDS ring
// (distance 3); LDS reads + BOTH waitcnts live inside one volatile asm whose
// outputs the step math depends on. LDS addresses passed as 32-bit AS(3).
// ---------------------------------------------------------------------------
__device__ __forceinline__ void mzi(const float4 t, v2& a, v2& b)
{
    v2 P  = to2(t.x, t.y) * to2(a.x, a.x) + to2(-t.y, t.x) * to2(a.y, a.y);
    v2 na = to2(t.z, t.z) * P + to2(-t.w, t.w) * to2(b.y, b.x);
    b     = to2(t.z, t.z) * b + to2(-t.w, t.w) * to2(P.y, P.x);
    a = na;
}

__device__ __forceinline__ void step(v2* x, const float4* T, int lane)
{
    mzi(T[0], x[0], x[1]);
    mzi(T[7], x[14], x[15]);
    float rc0r  = __shfl_down(x[0].x, 1, 64);
    float rc0i  = __shfl_down(x[0].y, 1, 64);
    float lc15r = __shfl_up(x[15].x, 1, 64);
    float lc15i = __shfl_up(x[15].y, 1, 64);
    float blx = __shfl_up(T[15].x, 1, 64);
    float bly = __shfl_up(T[15].y, 1, 64);
    float blz = __shfl_up(T[15].z, 1, 64);
    float blw = __shfl_up(T[15].w, 1, 64);
    if (lane == 0) { blx = 1.f; bly = 0.f; blz = 1.f; blw = 0.f; }
#pragma unroll
    for (int j = 1; j < 7; ++j) mzi(T[j], x[2 * j], x[2 * j + 1]);
#pragma unroll
    for (int j = 0; j < 7; ++j) mzi(T[8 + j], x[2 * j + 1], x[2 * j + 2]);
    {
        const float4 t = T[15];
        v2 P = to2(t.x, t.y) * to2(x[15].x, x[15].x) + to2(-t.y, t.x) * to2(x[15].y, x[15].y);
        x[15] = to2(t.z, t.z) * P + to2(-t.w, t.w) * to2(rc0i, rc0r);
    }
    {
        v2 P = to2(blx, bly) * to2(lc15r, lc15r) + to2(-bly, blx) * to2(lc15i, lc15i);
        x[0] = to2(blz, blz) * x[0] + to2(-blw, blw) * to2(P.y, P.x);
    }
}

#define GLOBAL_AS const __attribute__((address_space(1))) void*
#define LDS_AS    __attribute__((address_space(3))) void*

// DMA one layer (16 KB) into ring slot s: lane lands at row base + lane*16.
#define ISSUE(lidx, s)                                                        \
    do {                                                                      \
        const float4* _src = lanep + (size_t)(lidx) * TAB_F4_PER_L;           \
        _Pragma("unroll") for (int _j = 0; _j < 16; ++_j)                     \
            __builtin_amdgcn_global_load_lds(                                 \
                (GLOBAL_AS)(_src + _j * 64),                                  \
                (LDS_AS)&smem[s][_j][0], 16, 0, 0);                           \
    } while (0)

// Wait for this slot's DMA (vmcnt 32 = two newer layers still in flight),
// read 16 float4 from LDS, wait lgkmcnt 0 — all inside ONE asm so the step
// math (which consumes the outputs) is ordered after both waits by dataflow.
// slota is a 32-bit LDS address (single VGPR).
#define DSREAD(T, slota)                                                      \
    asm volatile(                                                             \
        "s_waitcnt vmcnt(32)\n\t"                                            \
        "ds_read_b128 %0, %16\n\t"                                           \
        "ds_read_b128 %1, %16 offset:1024\n\t"                               \
        "ds_read_b128 %2, %16 offset:2048\n\t"                               \
        "ds_read_b128 %3, %16 offset:3072\n\t"                               \
        "ds_read_b128 %4, %16 offset:4096\n\t"                               \
        "ds_read_b128 %5, %16 offset:5120\n\t"                               \
        "ds_read_b128 %6, %16 offset:6144\n\t"                               \
        "ds_read_b128 %7, %16 offset:7168\n\t"                               \
        "ds_read_b128 %8, %16 offset:8192\n\t"                               \
        "ds_read_b128 %9, %16 offset:9216\n\t"                               \
        "ds_read_b128 %10, %16 offset:10240\n\t"                             \
        "ds_read_b128 %11, %16 offset:11264\n\t"                             \
        "ds_read_b128 %12, %16 offset:12288\n\t"                             \
        "ds_read_b128 %13, %16 offset:13312\n\t"                             \
        "ds_read_b128 %14, %16 offset:14336\n\t"                             \
        "ds_read_b128 %15, %16 offset:15360\n\t"                             \
        "s_waitcnt lgkmcnt(0)"                                               \
        : "=&v"(T[0]), "=&v"(T[1]), "=&v"(T[2]), "=&v"(T[3]),                 \
          "=&v"(T[4]), "=&v"(T[5]), "=&v"(T[6]), "=&v"(T[7]),                 \
          "=&v"(T[8]), "=&v"(T[9]), "=&v"(T[10]), "=&v"(T[11]),               \
          "=&v"(T[12]), "=&v"(T[13]), "=&v"(T[14]), "=&v"(T[15])              \
        : "v"(slota))

__global__ __launch_bounds__(64, 1) void mesh_kernel(
    const float* __restrict__ stateR, const float* __restrict__ stateI,
    const float* __restrict__ omega,  const float* __restrict__ mod_bias,
    const float* __restrict__ ws, float* __restrict__ out)
{
    __shared__ float4 smem[4][16][64];   // 4-slot ring, 16 KB/slot

    const int b = blockIdx.x;
    const int lane = threadIdx.x;
    const float4* lanep = (const float4*)ws + lane;

    v2 x[16];
    {
        const float4* sr4 = (const float4*)(stateR + b * NH + lane * 16);
        const float4* si4 = (const float4*)(stateI + b * NH + lane * 16);
#pragma unroll
        for (int q = 0; q < 4; ++q) {
            float4 r = sr4[q], i = si4[q];
            x[4 * q + 0] = to2(r.x, i.x);
            x[4 * q + 1] = to2(r.y, i.y);
            x[4 * q + 2] = to2(r.z, i.z);
            x[4 * q + 3] = to2(r.w, i.w);
        }
    }
    // Force the compiler's waitcnt for the state loads to land HERE, before
    // any DMA is issued.
    asm volatile("" ::
        "v"(x[0]), "v"(x[1]), "v"(x[2]), "v"(x[3]),
        "v"(x[4]), "v"(x[5]), "v"(x[6]), "v"(x[7]),
        "v"(x[8]), "v"(x[9]), "v"(x[10]), "v"(x[11]),
        "v"(x[12]), "v"(x[13]), "v"(x[14]), "v"(x[15]));

    // 32-bit LDS addresses (AS3) for the 4 slot rows of this lane
    unsigned s0a = (unsigned)(size_t)(LDS_AS)&smem[0][0][lane];
    unsigned s1a = (unsigned)(size_t)(LDS_AS)&smem[1][0][lane];
    unsigned s2a = (unsigned)(size_t)(LDS_AS)&smem[2][0][lane];
    unsigned s3a = (unsigned)(size_t)(LDS_AS)&smem[3][0][lane];

    ISSUE(0, 0);
    ISSUE(1, 1);
    ISSUE(2, 2);

    float4 T[16];
#pragma unroll 1
    for (int l = 0; l < NSTEPS; l += 4) {
        // Tail ISSUEs (layers 128..130) read into the ih block: in-bounds,
        // written to slots that are never consumed again.
        DSREAD(T, s0a); ISSUE(l + 3, 3); step(x, T, lane);
        DSREAD(T, s1a); ISSUE(l + 4, 0); step(x, T, lane);
        DSREAD(T, s2a); ISSUE(l + 5, 1); step(x, T, lane);
        DSREAD(T, s3a); ISSUE(l + 6, 2); step(x, T, lane);
    }

    // epilogue: phase, + ih, modReLU (compiler's own waits drain tail DMAs)
    float om[16], mb[16];
#pragma unroll
    for (int q = 0; q < 4; ++q) {
        float4 o = ((const float4*)(omega + lane * 16))[q];
        float4 m = ((const float4*)(mod_bias + lane * 16))[q];
        om[4 * q] = o.x; om[4 * q + 1] = o.y; om[4 * q + 2] = o.z; om[4 * q + 3] = o.w;
        mb[4 * q] = m.x; mb[4 * q + 1] = m.y; mb[4 * q + 2] = m.z; mb[4 * q + 3] = m.w;
    }
    float o0[16], o1[16];
    const float4* ihp = (const float4*)(ws + IH_OFF + b * NH * 2) + lane * 8;
#pragma unroll
    for (int q = 0; q < 8; ++q) {
        float4 ih2 = ihp[q];   // {R,I} for channels 2q, 2q+1
#pragma unroll
        for (int e = 0; e < 2; ++e) {
            int j = 2 * q + e;
            float ihr = (e == 0) ? ih2.x : ih2.z;
            float ihi = (e == 0) ? ih2.y : ih2.w;
            float so, co;
            __sincosf(om[j], &so, &co);
            float zr = ihr + co * x[j].x - so * x[j].y;
            float zi = ihi + so * x[j].x + co * x[j].y;
            float mag = sqrtf(zr * zr + zi * zi);
            float sc = fmaxf(mag + mb[j], 0.f) / fmaxf(mag, 1e-8f);
            o0[j] = sc * zr;
            o1[j] = sc * zi;
        }
    }
#pragma unroll
    for (int q = 0; q < 4; ++q) {
        ((float4*)(out + b * NH + lane * 16))[q] =
            make_float4(o0[4 * q], o0[4 * q + 1], o0[4 * q + 2], o0[4 * q + 3]);
        ((float4*)(out + NBATCH * NH + b * NH + lane * 16))[q] =
            make_float4(o1[4 * q], o1[4 * q + 1], o1[4 * q + 2], o1[4 * q + 3]);
    }
}

// ---------------------------------------------------------------------------
extern "C" void kernel_launch(void* const* d_in, const int* in_sizes, int n_in,
                              void* d_out, int out_size, void* d_ws, size_t ws_size,
                              hipStream_t stream)
{
    const float* inputsR = (const float*)d_in[0];
    const float* inputsI = (const float*)d_in[1];
    const float* stateR  = (const float*)d_in[2];
    const float* stateI  = (const float*)d_in[3];
    const float* weightR = (const float*)d_in[4];
    const float* weightI = (const float*)d_in[5];
    const float* biasR   = (const float*)d_in[6];
    const float* biasI   = (const float*)d_in[7];
    const float* angleA0 = (const float*)d_in[8];
    const float* angleA1 = (const float*)d_in[9];
    const float* angleB0 = (const float*)d_in[10];
    const float* angleB1 = (const float*)d_in[11];
    const float* omega   = (const float*)d_in[12];
    const float* mod_b   = (const float*)d_in[13];
    float* ws = (float*)d_ws;
    float* out = (float*)d_out;

    hipLaunchKernelGGL(prep_kernel, dim3(GEMM_BLOCKS + TRIG_BLOCKS), dim3(256),
                       0, stream, inputsR, inputsI, weightR, weightI,
                       biasR, biasI, angleA0, angleA1, angleB0, angleB1, ws);
    hipLaunchKernelGGL(mesh_kernel, dim3(NBATCH), dim3(64), 0, stream,
                       stateR, stateI, omega, mod_b, ws, out);
}